// Round 6
// baseline (127.661 us; speedup 1.0000x reference)
//
#include <hip/hip_runtime.h>

// SQDDPG mixer, MI355X. Round 11: R7 structure with the nh-split
// materialized across waves: 512-thread blocks (8 waves), wave w owns
// columns X in {2w, 2w+1}. (512,4) => 2 blocks/CU x 8 waves = 16 waves/CU
// and 128-reg budget — both identical to R7 — but per-thread serial work
// halves (layer-1 MFMA 80->40, layer-2 LDS reads 128->64, scatter 64->32).
// Chip-wide traffic unchanged. Grid 1024 = 2 clean rounds of 512.
//
// FROZEN (R8/R10 lessons): main needs 16 waves/CU, <=128 regs/thread, no
// partial dispatch tail. R4/R6: watch symmetric FETCH/WRITE = spill.
// Frozen validated facts (R2/R3): threefry partitionable, bits=o0^o1,
// counter (0, b*128+n); stable ranks; coalition slot j <- qs[inv_l[j]];
// output agent n reads prefix-row pos_l[n]; B-frag pack order: slot
// (t,u,L) elem j -> B[k=t*32+(L>>4)*8+j][n=u*16+(L&15)].
// Frozen validated facts (R6/R7): row map M-row = prefix*8+(s&7), pass
// p = s>>3; tile mt holds prefixes {2mt,2mt+1}; K-slice t contributes iff
// t<=mt; diagonal mask on = (q>>1)<=(l15>>3); h1 swizzle: unit index
// u = ub + ((q*4+r)^xr), ub=((X>>1)*4+mt)*64+(hi<<4), hi=(X&1)*2+sl,
// xr=(q>>1)|((hi&1)<<1), elem j=s7; reader lane Lsw = L ^ ((L>>3)&3);
// gather marg_l[(s>>3)*64 + pos*8 + (s&7)].

#define A_N   8
#define NA_N  16
#define S_N   16
#define SD    256
#define EMB   256
#define B_TOT 1024

typedef __bf16 bf16x8 __attribute__((ext_vector_type(8)));
typedef float  f32x4  __attribute__((ext_vector_type(4)));

__device__ __forceinline__ f32x4 splat4(float v) {
  f32x4 x; x[0] = v; x[1] = v; x[2] = v; x[3] = v; return x;
}
__device__ __forceinline__ bf16x8 zero8() {
  bf16x8 z;
#pragma unroll
  for (int j = 0; j < 8; ++j) z[j] = (__bf16)0.0f;
  return z;
}

// ---------------------------------------------------------------------------
// JAX threefry2x32, key = (0, 42); partitionable draw: bits = o0 ^ o1.
// ---------------------------------------------------------------------------
__device__ __forceinline__ float jax_uniform(unsigned idx) {
  const unsigned ks0 = 0u, ks1 = 42u, ks2 = 0x1BD11BDAu ^ 42u;
  unsigned x0 = 0u + ks0;
  unsigned x1 = idx + ks1;
#define TF_RND(r) { x0 += x1; x1 = (x1 << (r)) | (x1 >> (32 - (r))); x1 ^= x0; }
  TF_RND(13) TF_RND(15) TF_RND(26) TF_RND(6)  x0 += ks1; x1 += ks2 + 1u;
  TF_RND(17) TF_RND(29) TF_RND(16) TF_RND(24) x0 += ks2; x1 += ks0 + 2u;
  TF_RND(13) TF_RND(15) TF_RND(26) TF_RND(6)  x0 += ks0; x1 += ks1 + 3u;
  TF_RND(17) TF_RND(29) TF_RND(16) TF_RND(24) x0 += ks1; x1 += ks2 + 4u;
  TF_RND(13) TF_RND(15) TF_RND(26) TF_RND(6)  x0 += ks2; x1 += ks0 + 5u;
#undef TF_RND
  const unsigned bits = x0 ^ x1;
  return __uint_as_float((bits >> 9) | 0x3F800000u) - 1.0f;
}

// ---------------------------------------------------------------------------
// Merged prep (blocks 0..511: sW + V-net, 2 b each) + pack (blocks 512..559).
// Exact R7 form (117.2 us session best).
// ---------------------------------------------------------------------------
__global__ __launch_bounds__(256) void prep_pack_kernel(
    const float* __restrict__ states, const float* __restrict__ W1,
    const float* __restrict__ b1, const float* __restrict__ Vw1,
    const float* __restrict__ Vb1, const float* __restrict__ Vw2,
    const float* __restrict__ Vb2, const float* __restrict__ W2,
    float* __restrict__ sW, float* __restrict__ vout,
    __bf16* __restrict__ W1b_bf, __bf16* __restrict__ W2_bf) {
  __shared__ float st_l[2][SD];
  __shared__ float red_l[2][4];

  if (blockIdx.x >= 512) {  // ---- pack path ----
    const int ts = (blockIdx.x - 512) * 256 + threadIdx.x;  // 0..12287
    if (ts < 4096) {                                // W1 bottom: t=0..3
      const int t = ts >> 10, rem = ts & 1023, u = rem >> 6, Lp = rem & 63;
      const int qp = Lp >> 4, l15p = Lp & 15;
#pragma unroll
      for (int j = 0; j < 8; ++j) {
        const int k = t * 32 + qp * 8 + j, nn = u * 16 + l15p;
        W1b_bf[ts * 8 + j] = (__bf16)W1[(SD + k) * EMB + nn];
      }
    } else {                                        // W2: t=0..7
      const int ts2 = ts - 4096;
      const int t = ts2 >> 10, rem = ts2 & 1023, u = rem >> 6, Lp = rem & 63;
      const int qp = Lp >> 4, l15p = Lp & 15;
#pragma unroll
      for (int j = 0; j < 8; ++j) {
        const int k = t * 32 + qp * 8 + j, nn = u * 16 + l15p;
        W2_bf[ts2 * 8 + j] = (__bf16)W2[k * EMB + nn];
      }
    }
    return;
  }

  // ---- prep path ----
  const int b0 = blockIdx.x * 2;
  const int n = threadIdx.x;

#pragma unroll
  for (int i = 0; i < 2; ++i) st_l[i][n] = states[(b0 + i) * SD + n];
  __syncthreads();

  float aS[2], aV[2];
  const float b1n = b1[n], vb1n = Vb1[n];
#pragma unroll
  for (int i = 0; i < 2; ++i) { aS[i] = b1n; aV[i] = vb1n; }

#pragma unroll 8
  for (int k = 0; k < SD; ++k) {
    const float wv = W1[k * EMB + n];
    const float vw = Vw1[k * EMB + n];
#pragma unroll
    for (int i = 0; i < 2; ++i) {
      const float s = st_l[i][k];
      aS[i] = fmaf(s, wv, aS[i]);
      aV[i] = fmaf(s, vw, aV[i]);
    }
  }
#pragma unroll
  for (int i = 0; i < 2; ++i) sW[(b0 + i) * EMB + n] = aS[i];

  const float vw2 = Vw2[n];
#pragma unroll
  for (int i = 0; i < 2; ++i) {
    float c = fmaxf(aV[i], 0.f) * vw2;
#pragma unroll
    for (int off = 32; off; off >>= 1) c += __shfl_down(c, off);
    if ((n & 63) == 0) red_l[i][n >> 6] = c;
  }
  __syncthreads();
  if (n < 2)
    vout[b0 + n] = red_l[n][0] + red_l[n][1] + red_l[n][2] + red_l[n][3] + Vb2[0];
}

// ---------------------------------------------------------------------------
// Main: 1024 blocks (one per b), 512 threads = 8 waves, (512,4) -> 2
// blocks/CU = 16 waves/CU, 128-reg budget. Wave w owns columns X=2w,2w+1.
// Two passes of M=64, prefix-major rows, triangular layer-1.
// ---------------------------------------------------------------------------
__global__ __launch_bounds__(512, 4) void main_kernel(
    const float* __restrict__ agent_qs, const float* __restrict__ b2g,
    const float* __restrict__ W3, const float* __restrict__ b3,
    const float* __restrict__ sW, const float* __restrict__ vv,
    const __bf16* __restrict__ W1b_bf, const __bf16* __restrict__ W2_bf,
    float* __restrict__ out) {
  __shared__ bf16x8 h1_l[32 * 64];      // 32 KB: layer2 A-frags (swizzled)
  __shared__ __attribute__((aligned(16))) __bf16 qs_bf[A_N * NA_N];
  __shared__ float u_l[128];
  __shared__ int   inv_l[128];          // inv_l[s*8+a] = rank of agent a
  __shared__ int   pos_l[128];          // pos_l[s*8+r] = agent with rank r
  __shared__ float adv_part[8][64];
  __shared__ float marg_l[128];         // marg_l[p*64 + prefix*8 + (s&7)]

  const int b = blockIdx.x;
  const int n = threadIdx.x;
  const int w = n >> 6, L = n & 63, q = L >> 4, l15 = L & 15;  // w in 0..7
  const int s7 = l15 & 7;        // s low bits (A-frag / C-row role)
  const int sl = l15 >> 3;       // prefix low bit (A-frag side)
  const int jq = q >> 1;         // jcoal low bit
  const int na0 = (q & 1) * 8;   // action sub-block
  const int Lsw = L ^ ((L >> 3) & 3);  // swizzled layer-2 read lane

  if (n < 128) {
    qs_bf[n] = (__bf16)agent_qs[b * 128 + n];
    u_l[n] = jax_uniform((unsigned)(b * 128 + n));
  }
  __syncthreads();

  if (n < 128) {
    const int s = n >> 3, a = n & 7;
    const float u = u_l[n];
    int r = 0;
#pragma unroll
    for (int a2 = 0; a2 < A_N; ++a2) {
      const float u2 = u_l[s * 8 + a2];
      r += (u2 < u || (u2 == u && a2 < a)) ? 1 : 0;
    }
    inv_l[n] = r;
    pos_l[s * 8 + r] = a;
  }
  __syncthreads();

  // diagonal-tile mask: t==mt -> on iff jcoal<=prefix iff jq<=sl
  const bool diag_on = (jq <= sl);

#pragma unroll 1
  for (int p = 0; p < 2; ++p) {
    const int invbase = (p * 8 + s7) * 8;

    // ---- layer 1: triangular (64x128)@W1b(128x256); X = 2w+i ----
    {
      f32x4 acc[4][2];
#pragma unroll
      for (int i = 0; i < 2; ++i) {
        const float sv = sW[b * EMB + (w * 2 + i) * 16 + l15];
#pragma unroll
        for (int mt = 0; mt < 4; ++mt) acc[mt][i] = splat4(sv);
      }
#pragma unroll
      for (int t = 0; t < 4; ++t) {
        const int ag = inv_l[invbase + 2 * t + jq];
        const bf16x8 afb = *(const bf16x8*)&qs_bf[ag * NA_N + na0];
        const bf16x8 afd = diag_on ? afb : zero8();
        bf16x8 bfr[2];
#pragma unroll
        for (int i = 0; i < 2; ++i)
          bfr[i] = *(const bf16x8*)
              &W1b_bf[((t * 16 + w * 2 + i) * 64 + L) * 8];
#pragma unroll
        for (int mt = 0; mt < 4; ++mt) {
          if (mt < t) continue;  // compile-time folded: t>mt is exact zero
#pragma unroll
          for (int i = 0; i < 2; ++i)
            acc[mt][i] = __builtin_amdgcn_mfma_f32_16x16x32_bf16(
                (mt == t) ? afd : afb, bfr[i], acc[mt][i], 0, 0, 0);
        }
      }
      // relu -> bf16 swizzled scatter (R6-validated formula, X = 2w+i)
      __bf16* h1e = (__bf16*)h1_l;
#pragma unroll
      for (int i = 0; i < 2; ++i) {
        const int hi = i * 2 + sl;                 // (X&1)*2 + sl
        const int xr = (q >> 1) | ((hi & 1) << 1);
#pragma unroll
        for (int mt = 0; mt < 4; ++mt) {
          const int ub = (w * 4 + mt) * 64 + (hi << 4);  // (X>>1)=w
#pragma unroll
          for (int r = 0; r < 4; ++r) {
            const float v = fmaxf(acc[mt][i][r], 0.f);
            const int u = ub + ((q * 4 + r) ^ xr);
            h1e[u * 8 + s7] = (__bf16)v;
          }
        }
      }
    }
    __syncthreads();

    // ---- layer 2 + layer 3 partials: X = 2w+i, psum over i ----
    float psum[4][4];
#pragma unroll
    for (int mt = 0; mt < 4; ++mt)
#pragma unroll
      for (int r = 0; r < 4; ++r) psum[mt][r] = 0.f;

    {
      f32x4 acc[4][2];
#pragma unroll
      for (int i = 0; i < 2; ++i) {
        const float bv = b2g[(w * 2 + i) * 16 + l15];
#pragma unroll
        for (int mt = 0; mt < 4; ++mt) acc[mt][i] = splat4(bv);
      }
#pragma unroll 2
      for (int t = 0; t < 8; ++t) {
        bf16x8 bfr[2];
#pragma unroll
        for (int i = 0; i < 2; ++i)
          bfr[i] = *(const bf16x8*)
              &W2_bf[((t * 16 + w * 2 + i) * 64 + L) * 8];
#pragma unroll
        for (int mt = 0; mt < 4; ++mt) {
          const bf16x8 af = h1_l[(t * 4 + mt) * 64 + Lsw];
#pragma unroll
          for (int i = 0; i < 2; ++i)
            acc[mt][i] = __builtin_amdgcn_mfma_f32_16x16x32_bf16(
                af, bfr[i], acc[mt][i], 0, 0, 0);
        }
      }
#pragma unroll
      for (int i = 0; i < 2; ++i) {
        const float w3v = W3[(w * 2 + i) * 16 + l15];
#pragma unroll
        for (int mt = 0; mt < 4; ++mt)
#pragma unroll
          for (int r = 0; r < 4; ++r)
            psum[mt][r] = fmaf(fmaxf(acc[mt][i][r], 0.f), w3v, psum[mt][r]);
      }
    }

    // ---- reduce 16 cols per quad, combine 8 waves via LDS ----
#pragma unroll
    for (int mt = 0; mt < 4; ++mt) {
#pragma unroll
      for (int r = 0; r < 4; ++r) {
        float sum = psum[mt][r];
#pragma unroll
        for (int off = 1; off < 16; off <<= 1) sum += __shfl_xor(sum, off);
        if (l15 == 0) adv_part[w][mt * 16 + q * 4 + r] = sum;
      }
    }
    __syncthreads();
    if (n < 64)
      marg_l[p * 64 + n] = adv_part[0][n] + adv_part[1][n] + adv_part[2][n] +
                           adv_part[3][n] + adv_part[4][n] + adv_part[5][n] +
                           adv_part[6][n] + adv_part[7][n];
    __syncthreads();
  }

  // ---- gather: agent a at sample s -> row prefix*8 + (s&7), p = s>>3 ----
  if (n < A_N) {
    float sh = 0.f;
#pragma unroll
    for (int s = 0; s < S_N; ++s) {
      const int pr = pos_l[s * 8 + n];
      sh += marg_l[((s >> 3) << 6) + pr * 8 + (s & 7)];
    }
    out[b * A_N + n] = sh * (1.f / 16.f) + b3[0] + vv[b];
  }
}

// ---------------------------------------------------------------------------
extern "C" void kernel_launch(void* const* d_in, const int* in_sizes, int n_in,
                              void* d_out, int out_size, void* d_ws,
                              size_t ws_size, hipStream_t stream) {
  const float* states   = (const float*)d_in[0];
  const float* agent_qs = (const float*)d_in[1];
  const float* W1       = (const float*)d_in[2];
  const float* b1       = (const float*)d_in[3];
  const float* W2       = (const float*)d_in[4];
  const float* b2       = (const float*)d_in[5];
  const float* W3       = (const float*)d_in[6];
  const float* b3       = (const float*)d_in[7];
  const float* Vw1      = (const float*)d_in[8];
  const float* Vb1      = (const float*)d_in[9];
  const float* Vw2      = (const float*)d_in[10];
  const float* Vb2      = (const float*)d_in[11];
  float* out = (float*)d_out;

  char* ws = (char*)d_ws;
  float*  sW     = (float*)(ws);                     // 1 MB
  float*  vv     = (float*)(ws + 1048576);           // 4 KB
  __bf16* W1b_bf = (__bf16*)(ws + 1052672);          // 64 KB
  __bf16* W2_bf  = (__bf16*)(ws + 1118208);          // 128 KB

  prep_pack_kernel<<<560, 256, 0, stream>>>(states, W1, b1, Vw1, Vb1, Vw2,
                                            Vb2, W2, sW, vv, W1b_bf, W2_bf);
  main_kernel<<<B_TOT, 512, 0, stream>>>(agent_qs, b2, W3, b3, sW, vv,
                                         W1b_bf, W2_bf, out);
}

// Round 7
// 124.049 us; speedup vs baseline: 1.0291x; 1.0291x over previous
//
#include <hip/hip_runtime.h>

// SQDDPG mixer, MI355X. Round 12: main is FROZEN at R7 (117.2 us best;
// R8/R10/R11 all proved any residency change regresses). This round only
// rebuilds prep: 2-D tiling (64 b-groups x 8 col-groups = 512 A-blocks),
// each block reads a 32-col W1/Vw1 slice -> L2 traffic 268 MB -> 41 MB
// (~6 us -> ~2 us). K not split => sW bit-identical. V-net col-reduction
// becomes 8 per-block partials vpart[b][cg]; main gathers Vb2 + sum.
//
// FROZEN (R8/R10/R11): main = 256 thr, (256,4), 1024 blocks all
// co-resident, <=128 regs (acc[4][2] + nh un-halves). R4/R6: symmetric
// FETCH/WRITE = spill.
// Frozen validated facts (R2/R3): threefry partitionable, bits=o0^o1,
// counter (0, b*128+n); stable ranks; coalition slot j <- qs[inv_l[j]];
// output agent n reads prefix-row pos_l[n]; B-frag pack order: slot
// (t,u,L) elem j -> B[k=t*32+(L>>4)*8+j][n=u*16+(L&15)].
// Frozen validated facts (R6/R7): row map M-row = prefix*8+(s&7), pass
// p = s>>3; tile mt holds prefixes {2mt,2mt+1}; K-slice t contributes iff
// t<=mt; diagonal mask on = (q>>1)<=(l15>>3); h1 swizzle: unit index
// u = ub + ((q*4+r)^xr), reader lane Lsw = L ^ ((L>>3)&3); gather
// marg_l[(s>>3)*64 + pos*8 + (s&7)].

#define A_N   8
#define NA_N  16
#define S_N   16
#define SD    256
#define EMB   256
#define B_TOT 1024

typedef __bf16 bf16x8 __attribute__((ext_vector_type(8)));
typedef float  f32x4  __attribute__((ext_vector_type(4)));

__device__ __forceinline__ f32x4 splat4(float v) {
  f32x4 x; x[0] = v; x[1] = v; x[2] = v; x[3] = v; return x;
}
__device__ __forceinline__ bf16x8 zero8() {
  bf16x8 z;
#pragma unroll
  for (int j = 0; j < 8; ++j) z[j] = (__bf16)0.0f;
  return z;
}

// ---------------------------------------------------------------------------
// JAX threefry2x32, key = (0, 42); partitionable draw: bits = o0 ^ o1.
// ---------------------------------------------------------------------------
__device__ __forceinline__ float jax_uniform(unsigned idx) {
  const unsigned ks0 = 0u, ks1 = 42u, ks2 = 0x1BD11BDAu ^ 42u;
  unsigned x0 = 0u + ks0;
  unsigned x1 = idx + ks1;
#define TF_RND(r) { x0 += x1; x1 = (x1 << (r)) | (x1 >> (32 - (r))); x1 ^= x0; }
  TF_RND(13) TF_RND(15) TF_RND(26) TF_RND(6)  x0 += ks1; x1 += ks2 + 1u;
  TF_RND(17) TF_RND(29) TF_RND(16) TF_RND(24) x0 += ks2; x1 += ks0 + 2u;
  TF_RND(13) TF_RND(15) TF_RND(26) TF_RND(6)  x0 += ks0; x1 += ks1 + 3u;
  TF_RND(17) TF_RND(29) TF_RND(16) TF_RND(24) x0 += ks1; x1 += ks2 + 4u;
  TF_RND(13) TF_RND(15) TF_RND(26) TF_RND(6)  x0 += ks2; x1 += ks0 + 5u;
#undef TF_RND
  const unsigned bits = x0 ^ x1;
  return __uint_as_float((bits >> 9) | 0x3F800000u) - 1.0f;
}

// ---------------------------------------------------------------------------
// Prep (blocks 0..511): 2-D tiled. Block = (bg, cg): 16 b's x 32 cols.
// Reads only the 32-col slice of W1-top/Vw1 (64 KB) + 16 states rows.
// Writes sW slice (full-K, bit-identical order) + vpart[b][cg] V-partials.
// Pack (blocks 512..559): unchanged bf16 B-frag repack.
// ---------------------------------------------------------------------------
__global__ __launch_bounds__(256) void prep_pack_kernel(
    const float* __restrict__ states, const float* __restrict__ W1,
    const float* __restrict__ b1, const float* __restrict__ Vw1,
    const float* __restrict__ Vb1, const float* __restrict__ Vw2,
    const float* __restrict__ W2,
    float* __restrict__ sW, float* __restrict__ vpart,
    __bf16* __restrict__ W1b_bf, __bf16* __restrict__ W2_bf) {
  __shared__ float st_l[16][257];   // +1 pad: rows land on distinct banks

  if (blockIdx.x >= 512) {  // ---- pack path ----
    const int ts = (blockIdx.x - 512) * 256 + threadIdx.x;  // 0..12287
    if (ts < 4096) {                                // W1 bottom: t=0..3
      const int t = ts >> 10, rem = ts & 1023, u = rem >> 6, Lp = rem & 63;
      const int qp = Lp >> 4, l15p = Lp & 15;
#pragma unroll
      for (int j = 0; j < 8; ++j) {
        const int k = t * 32 + qp * 8 + j, nn = u * 16 + l15p;
        W1b_bf[ts * 8 + j] = (__bf16)W1[(SD + k) * EMB + nn];
      }
    } else {                                        // W2: t=0..7
      const int ts2 = ts - 4096;
      const int t = ts2 >> 10, rem = ts2 & 1023, u = rem >> 6, Lp = rem & 63;
      const int qp = Lp >> 4, l15p = Lp & 15;
#pragma unroll
      for (int j = 0; j < 8; ++j) {
        const int k = t * 32 + qp * 8 + j, nn = u * 16 + l15p;
        W2_bf[ts2 * 8 + j] = (__bf16)W2[k * EMB + nn];
      }
    }
    return;
  }

  // ---- prep path: block (bg, cg) ----
  const int bg = blockIdx.x >> 3, cg = blockIdx.x & 7;
  const int b0 = bg * 16;
  const int col = cg * 32 + (threadIdx.x & 31);
  const int rl = threadIdx.x >> 5;          // 0..7; rows rl and rl+8

  // stage 16 states rows (coalesced)
#pragma unroll
  for (int j = 0; j < 16; ++j) {
    const int idx = threadIdx.x + j * 256;  // 0..4095
    st_l[idx >> 8][idx & 255] = states[(b0 + (idx >> 8)) * SD + (idx & 255)];
  }
  __syncthreads();

  float aS0 = b1[col], aS1 = aS0;
  float aV0 = Vb1[col], aV1 = aV0;
  const int r0 = rl, r1 = rl + 8;
#pragma unroll 8
  for (int k = 0; k < SD; ++k) {
    const float wv = W1[k * EMB + col];
    const float vw = Vw1[k * EMB + col];
    const float sA = st_l[r0][k], sB = st_l[r1][k];
    aS0 = fmaf(sA, wv, aS0);
    aS1 = fmaf(sB, wv, aS1);
    aV0 = fmaf(sA, vw, aV0);
    aV1 = fmaf(sB, vw, aV1);
  }
  sW[(b0 + r0) * EMB + col] = aS0;
  sW[(b0 + r1) * EMB + col] = aS1;

  const float vw2 = Vw2[col];
  float c0 = fmaxf(aV0, 0.f) * vw2;
  float c1 = fmaxf(aV1, 0.f) * vw2;
#pragma unroll
  for (int off = 16; off; off >>= 1) {      // stays within 32-lane halves
    c0 += __shfl_xor(c0, off);
    c1 += __shfl_xor(c1, off);
  }
  if ((threadIdx.x & 31) == 0) {
    vpart[(b0 + r0) * 8 + cg] = c0;
    vpart[(b0 + r1) * 8 + cg] = c1;
  }
}

// ---------------------------------------------------------------------------
// Main: FROZEN R7 structure. 1024 blocks (one per b), 256 threads = 4
// waves, (256,4) -> all blocks co-resident at 4/CU. Two passes of M=64,
// prefix-major rows, triangular layer-1 (acc[4][2], nh-halved). Layer-2:
// nh-halved, psum carry. Only change vs R7: gather sums vpart + Vb2.
// ---------------------------------------------------------------------------
__global__ __launch_bounds__(256, 4) void main_kernel(
    const float* __restrict__ agent_qs, const float* __restrict__ b2g,
    const float* __restrict__ W3, const float* __restrict__ b3,
    const float* __restrict__ sW, const float* __restrict__ vpart,
    const float* __restrict__ Vb2,
    const __bf16* __restrict__ W1b_bf, const __bf16* __restrict__ W2_bf,
    float* __restrict__ out) {
  __shared__ bf16x8 h1_l[32 * 64];      // 32 KB: layer2 A-frags (swizzled)
  __shared__ __attribute__((aligned(16))) __bf16 qs_bf[A_N * NA_N];
  __shared__ float u_l[128];
  __shared__ int   inv_l[128];          // inv_l[s*8+a] = rank of agent a
  __shared__ int   pos_l[128];          // pos_l[s*8+r] = agent with rank r
  __shared__ float adv_part[4][64];
  __shared__ float marg_l[128];         // marg_l[p*64 + prefix*8 + (s&7)]

  const int b = blockIdx.x;
  const int n = threadIdx.x;
  const int w = n >> 6, L = n & 63, q = L >> 4, l15 = L & 15;
  const int s7 = l15 & 7;        // s low bits (A-frag / C-row role)
  const int sl = l15 >> 3;       // prefix low bit (A-frag side)
  const int jq = q >> 1;         // jcoal low bit
  const int na0 = (q & 1) * 8;   // action sub-block
  const int Lsw = L ^ ((L >> 3) & 3);  // swizzled layer-2 read lane

  if (n < 128) {
    qs_bf[n] = (__bf16)agent_qs[b * 128 + n];
    u_l[n] = jax_uniform((unsigned)(b * 128 + n));
  }
  __syncthreads();

  if (n < 128) {
    const int s = n >> 3, a = n & 7;
    const float u = u_l[n];
    int r = 0;
#pragma unroll
    for (int a2 = 0; a2 < A_N; ++a2) {
      const float u2 = u_l[s * 8 + a2];
      r += (u2 < u || (u2 == u && a2 < a)) ? 1 : 0;
    }
    inv_l[n] = r;
    pos_l[s * 8 + r] = a;
  }
  __syncthreads();

  // diagonal-tile mask: t==mt -> on iff jcoal<=prefix iff jq<=sl
  const bool diag_on = (jq <= sl);

#pragma unroll 1
  for (int p = 0; p < 2; ++p) {
    const int invbase = (p * 8 + s7) * 8;

    // ---- layer 1: triangular (64x128)@W1b(128x256); 2 un-halves ----
#pragma unroll 1
    for (int nh = 0; nh < 2; ++nh) {
      f32x4 acc[4][2];
#pragma unroll
      for (int i = 0; i < 2; ++i) {
        const float sv = sW[b * EMB + (w * 4 + nh * 2 + i) * 16 + l15];
#pragma unroll
        for (int mt = 0; mt < 4; ++mt) acc[mt][i] = splat4(sv);
      }
#pragma unroll
      for (int t = 0; t < 4; ++t) {
        const int ag = inv_l[invbase + 2 * t + jq];
        const bf16x8 afb = *(const bf16x8*)&qs_bf[ag * NA_N + na0];
        const bf16x8 afd = diag_on ? afb : zero8();
        bf16x8 bfr[2];
#pragma unroll
        for (int i = 0; i < 2; ++i)
          bfr[i] = *(const bf16x8*)
              &W1b_bf[((t * 16 + w * 4 + nh * 2 + i) * 64 + L) * 8];
#pragma unroll
        for (int mt = 0; mt < 4; ++mt) {
          if (mt < t) continue;  // compile-time folded: t>mt is exact zero
#pragma unroll
          for (int i = 0; i < 2; ++i)
            acc[mt][i] = __builtin_amdgcn_mfma_f32_16x16x32_bf16(
                (mt == t) ? afd : afb, bfr[i], acc[mt][i], 0, 0, 0);
        }
      }
      // relu -> bf16 swizzled scatter (conflict-free; R6-validated formula)
      __bf16* h1e = (__bf16*)h1_l;
#pragma unroll
      for (int i = 0; i < 2; ++i) {
        const int X = w * 4 + nh * 2 + i;
        const int hi = (X & 1) * 2 + sl;
        const int xr = (q >> 1) | ((hi & 1) << 1);
#pragma unroll
        for (int mt = 0; mt < 4; ++mt) {
          const int ub = ((X >> 1) * 4 + mt) * 64 + (hi << 4);
#pragma unroll
          for (int r = 0; r < 4; ++r) {
            const float v = fmaxf(acc[mt][i][r], 0.f);
            const int u = ub + ((q * 4 + r) ^ xr);
            h1e[u * 8 + s7] = (__bf16)v;
          }
        }
      }
    }
    __syncthreads();

    // ---- layer 2 + layer 3 partials: 2 un-halves, psum across halves ----
    float psum[4][4];
#pragma unroll
    for (int mt = 0; mt < 4; ++mt)
#pragma unroll
      for (int r = 0; r < 4; ++r) psum[mt][r] = 0.f;

#pragma unroll 1
    for (int nh = 0; nh < 2; ++nh) {
      f32x4 acc[4][2];
#pragma unroll
      for (int i = 0; i < 2; ++i) {
        const float bv = b2g[(w * 4 + nh * 2 + i) * 16 + l15];
#pragma unroll
        for (int mt = 0; mt < 4; ++mt) acc[mt][i] = splat4(bv);
      }
#pragma unroll 2
      for (int t = 0; t < 8; ++t) {
        bf16x8 bfr[2];
#pragma unroll
        for (int i = 0; i < 2; ++i)
          bfr[i] = *(const bf16x8*)
              &W2_bf[((t * 16 + w * 4 + nh * 2 + i) * 64 + L) * 8];
#pragma unroll
        for (int mt = 0; mt < 4; ++mt) {
          const bf16x8 af = h1_l[(t * 4 + mt) * 64 + Lsw];
#pragma unroll
          for (int i = 0; i < 2; ++i)
            acc[mt][i] = __builtin_amdgcn_mfma_f32_16x16x32_bf16(
                af, bfr[i], acc[mt][i], 0, 0, 0);
        }
      }
#pragma unroll
      for (int i = 0; i < 2; ++i) {
        const float w3v = W3[(w * 4 + nh * 2 + i) * 16 + l15];
#pragma unroll
        for (int mt = 0; mt < 4; ++mt)
#pragma unroll
          for (int r = 0; r < 4; ++r)
            psum[mt][r] = fmaf(fmaxf(acc[mt][i][r], 0.f), w3v, psum[mt][r]);
      }
    }

    // ---- reduce 16 cols per quad, combine waves via LDS ----
#pragma unroll
    for (int mt = 0; mt < 4; ++mt) {
#pragma unroll
      for (int r = 0; r < 4; ++r) {
        float sum = psum[mt][r];
#pragma unroll
        for (int off = 1; off < 16; off <<= 1) sum += __shfl_xor(sum, off);
        if (l15 == 0) adv_part[w][mt * 16 + q * 4 + r] = sum;
      }
    }
    __syncthreads();
    if (n < 64)
      marg_l[p * 64 + n] = adv_part[0][n] + adv_part[1][n] +
                           adv_part[2][n] + adv_part[3][n];
    __syncthreads();
  }

  // ---- gather: agent a at sample s -> row prefix*8 + (s&7), p = s>>3 ----
  if (n < A_N) {
    float sh = 0.f;
#pragma unroll
    for (int s = 0; s < S_N; ++s) {
      const int pr = pos_l[s * 8 + n];
      sh += marg_l[((s >> 3) << 6) + pr * 8 + (s & 7)];
    }
    float vvb = Vb2[0];
#pragma unroll
    for (int g = 0; g < 8; ++g) vvb += vpart[b * 8 + g];
    out[b * A_N + n] = sh * (1.f / 16.f) + b3[0] + vvb;
  }
}

// ---------------------------------------------------------------------------
extern "C" void kernel_launch(void* const* d_in, const int* in_sizes, int n_in,
                              void* d_out, int out_size, void* d_ws,
                              size_t ws_size, hipStream_t stream) {
  const float* states   = (const float*)d_in[0];
  const float* agent_qs = (const float*)d_in[1];
  const float* W1       = (const float*)d_in[2];
  const float* b1       = (const float*)d_in[3];
  const float* W2       = (const float*)d_in[4];
  const float* b2       = (const float*)d_in[5];
  const float* W3       = (const float*)d_in[6];
  const float* b3       = (const float*)d_in[7];
  const float* Vw1      = (const float*)d_in[8];
  const float* Vb1      = (const float*)d_in[9];
  const float* Vw2      = (const float*)d_in[10];
  const float* Vb2      = (const float*)d_in[11];
  float* out = (float*)d_out;

  char* ws = (char*)d_ws;
  float*  sW     = (float*)(ws);                     // 1 MB
  float*  vpart  = (float*)(ws + 1048576);           // 32 KB
  __bf16* W1b_bf = (__bf16*)(ws + 1081344);          // 64 KB
  __bf16* W2_bf  = (__bf16*)(ws + 1146880);          // 128 KB

  prep_pack_kernel<<<560, 256, 0, stream>>>(states, W1, b1, Vw1, Vb1, Vw2,
                                            W2, sW, vpart, W1b_bf, W2_bf);
  main_kernel<<<B_TOT, 256, 0, stream>>>(agent_qs, b2, W3, b3, sW, vpart,
                                         Vb2, W1b_bf, W2_bf, out);
}

// Round 8
// 119.281 us; speedup vs baseline: 1.0703x; 1.0400x over previous
//
#include <hip/hip_runtime.h>

// SQDDPG mixer, MI355X. Round 13: prep/pack reverted to R7 exact (3 prep
// experiments all regressed -> prep is overlapped with the ~80 us of
// harness HBM-roofline fills; its L2 traffic is off the critical path).
// Main = R7 with ONE surgical change: layer-1 A-frags (afb/afd, scattered
// inv_l+qs_bf LDS gathers + selects) hoisted out of the nh loop — they are
// nh-invariant; R7 rebuilt them 2x per pass. Halves the worst-aliased LDS
// gathers on the latency-bound critical path (R11 PMC: MfmaUtil 17%,
// VALUBusy 28%, HBM 4% -> issue/latency-bound).
//
// FROZEN (R8/R10/R11/R12): main = 256 thr, (256,4), 1024 blocks all
// co-resident at 4/CU, <=128 regs (acc[4][2] + nh un-halves); prep = R7
// form. R4/R6: symmetric FETCH/WRITE = spill signature.
// Frozen validated facts (R2/R3): threefry partitionable, bits=o0^o1,
// counter (0, b*128+n); stable ranks; coalition slot j <- qs[inv_l[j]];
// output agent n reads prefix-row pos_l[n]; B-frag pack order: slot
// (t,u,L) elem j -> B[k=t*32+(L>>4)*8+j][n=u*16+(L&15)].
// Frozen validated facts (R6/R7): row map M-row = prefix*8+(s&7), pass
// p = s>>3; tile mt holds prefixes {2mt,2mt+1}; K-slice t contributes iff
// t<=mt; diagonal mask on = (q>>1)<=(l15>>3); h1 swizzle: unit index
// u = ub + ((q*4+r)^xr), reader lane Lsw = L ^ ((L>>3)&3); gather
// marg_l[(s>>3)*64 + pos*8 + (s&7)].

#define A_N   8
#define NA_N  16
#define S_N   16
#define SD    256
#define EMB   256
#define B_TOT 1024

typedef __bf16 bf16x8 __attribute__((ext_vector_type(8)));
typedef float  f32x4  __attribute__((ext_vector_type(4)));

__device__ __forceinline__ f32x4 splat4(float v) {
  f32x4 x; x[0] = v; x[1] = v; x[2] = v; x[3] = v; return x;
}
__device__ __forceinline__ bf16x8 zero8() {
  bf16x8 z;
#pragma unroll
  for (int j = 0; j < 8; ++j) z[j] = (__bf16)0.0f;
  return z;
}

// ---------------------------------------------------------------------------
// JAX threefry2x32, key = (0, 42); partitionable draw: bits = o0 ^ o1.
// ---------------------------------------------------------------------------
__device__ __forceinline__ float jax_uniform(unsigned idx) {
  const unsigned ks0 = 0u, ks1 = 42u, ks2 = 0x1BD11BDAu ^ 42u;
  unsigned x0 = 0u + ks0;
  unsigned x1 = idx + ks1;
#define TF_RND(r) { x0 += x1; x1 = (x1 << (r)) | (x1 >> (32 - (r))); x1 ^= x0; }
  TF_RND(13) TF_RND(15) TF_RND(26) TF_RND(6)  x0 += ks1; x1 += ks2 + 1u;
  TF_RND(17) TF_RND(29) TF_RND(16) TF_RND(24) x0 += ks2; x1 += ks0 + 2u;
  TF_RND(13) TF_RND(15) TF_RND(26) TF_RND(6)  x0 += ks0; x1 += ks1 + 3u;
  TF_RND(17) TF_RND(29) TF_RND(16) TF_RND(24) x0 += ks1; x1 += ks2 + 4u;
  TF_RND(13) TF_RND(15) TF_RND(26) TF_RND(6)  x0 += ks2; x1 += ks0 + 5u;
#undef TF_RND
  const unsigned bits = x0 ^ x1;
  return __uint_as_float((bits >> 9) | 0x3F800000u) - 1.0f;
}

// ---------------------------------------------------------------------------
// Merged prep (blocks 0..511: sW + V-net, 2 b each) + pack (blocks 512..559).
// Exact R7 form (117.2 us session best).
// ---------------------------------------------------------------------------
__global__ __launch_bounds__(256) void prep_pack_kernel(
    const float* __restrict__ states, const float* __restrict__ W1,
    const float* __restrict__ b1, const float* __restrict__ Vw1,
    const float* __restrict__ Vb1, const float* __restrict__ Vw2,
    const float* __restrict__ Vb2, const float* __restrict__ W2,
    float* __restrict__ sW, float* __restrict__ vout,
    __bf16* __restrict__ W1b_bf, __bf16* __restrict__ W2_bf) {
  __shared__ float st_l[2][SD];
  __shared__ float red_l[2][4];

  if (blockIdx.x >= 512) {  // ---- pack path ----
    const int ts = (blockIdx.x - 512) * 256 + threadIdx.x;  // 0..12287
    if (ts < 4096) {                                // W1 bottom: t=0..3
      const int t = ts >> 10, rem = ts & 1023, u = rem >> 6, Lp = rem & 63;
      const int qp = Lp >> 4, l15p = Lp & 15;
#pragma unroll
      for (int j = 0; j < 8; ++j) {
        const int k = t * 32 + qp * 8 + j, nn = u * 16 + l15p;
        W1b_bf[ts * 8 + j] = (__bf16)W1[(SD + k) * EMB + nn];
      }
    } else {                                        // W2: t=0..7
      const int ts2 = ts - 4096;
      const int t = ts2 >> 10, rem = ts2 & 1023, u = rem >> 6, Lp = rem & 63;
      const int qp = Lp >> 4, l15p = Lp & 15;
#pragma unroll
      for (int j = 0; j < 8; ++j) {
        const int k = t * 32 + qp * 8 + j, nn = u * 16 + l15p;
        W2_bf[ts2 * 8 + j] = (__bf16)W2[k * EMB + nn];
      }
    }
    return;
  }

  // ---- prep path ----
  const int b0 = blockIdx.x * 2;
  const int n = threadIdx.x;

#pragma unroll
  for (int i = 0; i < 2; ++i) st_l[i][n] = states[(b0 + i) * SD + n];
  __syncthreads();

  float aS[2], aV[2];
  const float b1n = b1[n], vb1n = Vb1[n];
#pragma unroll
  for (int i = 0; i < 2; ++i) { aS[i] = b1n; aV[i] = vb1n; }

#pragma unroll 8
  for (int k = 0; k < SD; ++k) {
    const float wv = W1[k * EMB + n];
    const float vw = Vw1[k * EMB + n];
#pragma unroll
    for (int i = 0; i < 2; ++i) {
      const float s = st_l[i][k];
      aS[i] = fmaf(s, wv, aS[i]);
      aV[i] = fmaf(s, vw, aV[i]);
    }
  }
#pragma unroll
  for (int i = 0; i < 2; ++i) sW[(b0 + i) * EMB + n] = aS[i];

  const float vw2 = Vw2[n];
#pragma unroll
  for (int i = 0; i < 2; ++i) {
    float c = fmaxf(aV[i], 0.f) * vw2;
#pragma unroll
    for (int off = 32; off; off >>= 1) c += __shfl_down(c, off);
    if ((n & 63) == 0) red_l[i][n >> 6] = c;
  }
  __syncthreads();
  if (n < 2)
    vout[b0 + n] = red_l[n][0] + red_l[n][1] + red_l[n][2] + red_l[n][3] + Vb2[0];
}

// ---------------------------------------------------------------------------
// Main: FROZEN R7 structure + A-frag hoist. 1024 blocks (one per b), 256
// threads = 4 waves, (256,4). Two passes of M=64, prefix-major rows,
// triangular layer-1 (acc[4][2], nh-halved); afb/afd hoisted (nh-invariant).
// ---------------------------------------------------------------------------
__global__ __launch_bounds__(256, 4) void main_kernel(
    const float* __restrict__ agent_qs, const float* __restrict__ b2g,
    const float* __restrict__ W3, const float* __restrict__ b3,
    const float* __restrict__ sW, const float* __restrict__ vv,
    const __bf16* __restrict__ W1b_bf, const __bf16* __restrict__ W2_bf,
    float* __restrict__ out) {
  __shared__ bf16x8 h1_l[32 * 64];      // 32 KB: layer2 A-frags (swizzled)
  __shared__ __attribute__((aligned(16))) __bf16 qs_bf[A_N * NA_N];
  __shared__ float u_l[128];
  __shared__ int   inv_l[128];          // inv_l[s*8+a] = rank of agent a
  __shared__ int   pos_l[128];          // pos_l[s*8+r] = agent with rank r
  __shared__ float adv_part[4][64];
  __shared__ float marg_l[128];         // marg_l[p*64 + prefix*8 + (s&7)]

  const int b = blockIdx.x;
  const int n = threadIdx.x;
  const int w = n >> 6, L = n & 63, q = L >> 4, l15 = L & 15;
  const int s7 = l15 & 7;        // s low bits (A-frag / C-row role)
  const int sl = l15 >> 3;       // prefix low bit (A-frag side)
  const int jq = q >> 1;         // jcoal low bit
  const int na0 = (q & 1) * 8;   // action sub-block
  const int Lsw = L ^ ((L >> 3) & 3);  // swizzled layer-2 read lane

  if (n < 128) {
    qs_bf[n] = (__bf16)agent_qs[b * 128 + n];
    u_l[n] = jax_uniform((unsigned)(b * 128 + n));
  }
  __syncthreads();

  if (n < 128) {
    const int s = n >> 3, a = n & 7;
    const float u = u_l[n];
    int r = 0;
#pragma unroll
    for (int a2 = 0; a2 < A_N; ++a2) {
      const float u2 = u_l[s * 8 + a2];
      r += (u2 < u || (u2 == u && a2 < a)) ? 1 : 0;
    }
    inv_l[n] = r;
    pos_l[s * 8 + r] = a;
  }
  __syncthreads();

  // diagonal-tile mask: t==mt -> on iff jcoal<=prefix iff jq<=sl
  const bool diag_on = (jq <= sl);

#pragma unroll 1
  for (int p = 0; p < 2; ++p) {
    const int invbase = (p * 8 + s7) * 8;

    // ---- A-frags: nh-invariant, hoisted (R13). Static t indexing. ----
    bf16x8 afb[4], afd[4];
#pragma unroll
    for (int t = 0; t < 4; ++t) {
      const int ag = inv_l[invbase + 2 * t + jq];
      afb[t] = *(const bf16x8*)&qs_bf[ag * NA_N + na0];
      afd[t] = diag_on ? afb[t] : zero8();
    }

    // ---- layer 1: triangular (64x128)@W1b(128x256); 2 un-halves ----
#pragma unroll 1
    for (int nh = 0; nh < 2; ++nh) {
      f32x4 acc[4][2];
#pragma unroll
      for (int i = 0; i < 2; ++i) {
        const float sv = sW[b * EMB + (w * 4 + nh * 2 + i) * 16 + l15];
#pragma unroll
        for (int mt = 0; mt < 4; ++mt) acc[mt][i] = splat4(sv);
      }
#pragma unroll
      for (int t = 0; t < 4; ++t) {
        bf16x8 bfr[2];
#pragma unroll
        for (int i = 0; i < 2; ++i)
          bfr[i] = *(const bf16x8*)
              &W1b_bf[((t * 16 + w * 4 + nh * 2 + i) * 64 + L) * 8];
#pragma unroll
        for (int mt = 0; mt < 4; ++mt) {
          if (mt < t) continue;  // compile-time folded: t>mt is exact zero
#pragma unroll
          for (int i = 0; i < 2; ++i)
            acc[mt][i] = __builtin_amdgcn_mfma_f32_16x16x32_bf16(
                (mt == t) ? afd[t] : afb[t], bfr[i], acc[mt][i], 0, 0, 0);
        }
      }
      // relu -> bf16 swizzled scatter (conflict-free; R6-validated formula)
      __bf16* h1e = (__bf16*)h1_l;
#pragma unroll
      for (int i = 0; i < 2; ++i) {
        const int X = w * 4 + nh * 2 + i;
        const int hi = (X & 1) * 2 + sl;
        const int xr = (q >> 1) | ((hi & 1) << 1);
#pragma unroll
        for (int mt = 0; mt < 4; ++mt) {
          const int ub = ((X >> 1) * 4 + mt) * 64 + (hi << 4);
#pragma unroll
          for (int r = 0; r < 4; ++r) {
            const float v = fmaxf(acc[mt][i][r], 0.f);
            const int u = ub + ((q * 4 + r) ^ xr);
            h1e[u * 8 + s7] = (__bf16)v;
          }
        }
      }
    }
    __syncthreads();

    // ---- layer 2 + layer 3 partials: 2 un-halves, psum across halves ----
    float psum[4][4];
#pragma unroll
    for (int mt = 0; mt < 4; ++mt)
#pragma unroll
      for (int r = 0; r < 4; ++r) psum[mt][r] = 0.f;

#pragma unroll 1
    for (int nh = 0; nh < 2; ++nh) {
      f32x4 acc[4][2];
#pragma unroll
      for (int i = 0; i < 2; ++i) {
        const float bv = b2g[(w * 4 + nh * 2 + i) * 16 + l15];
#pragma unroll
        for (int mt = 0; mt < 4; ++mt) acc[mt][i] = splat4(bv);
      }
#pragma unroll 2
      for (int t = 0; t < 8; ++t) {
        bf16x8 bfr[2];
#pragma unroll
        for (int i = 0; i < 2; ++i)
          bfr[i] = *(const bf16x8*)
              &W2_bf[((t * 16 + w * 4 + nh * 2 + i) * 64 + L) * 8];
#pragma unroll
        for (int mt = 0; mt < 4; ++mt) {
          const bf16x8 af = h1_l[(t * 4 + mt) * 64 + Lsw];
#pragma unroll
          for (int i = 0; i < 2; ++i)
            acc[mt][i] = __builtin_amdgcn_mfma_f32_16x16x32_bf16(
                af, bfr[i], acc[mt][i], 0, 0, 0);
        }
      }
#pragma unroll
      for (int i = 0; i < 2; ++i) {
        const float w3v = W3[(w * 4 + nh * 2 + i) * 16 + l15];
#pragma unroll
        for (int mt = 0; mt < 4; ++mt)
#pragma unroll
          for (int r = 0; r < 4; ++r)
            psum[mt][r] = fmaf(fmaxf(acc[mt][i][r], 0.f), w3v, psum[mt][r]);
      }
    }

    // ---- reduce 16 cols per quad, combine waves via LDS ----
#pragma unroll
    for (int mt = 0; mt < 4; ++mt) {
#pragma unroll
      for (int r = 0; r < 4; ++r) {
        float sum = psum[mt][r];
#pragma unroll
        for (int off = 1; off < 16; off <<= 1) sum += __shfl_xor(sum, off);
        if (l15 == 0) adv_part[w][mt * 16 + q * 4 + r] = sum;
      }
    }
    __syncthreads();
    if (n < 64)
      marg_l[p * 64 + n] = adv_part[0][n] + adv_part[1][n] +
                           adv_part[2][n] + adv_part[3][n];
    __syncthreads();
  }

  // ---- gather: agent a at sample s -> row prefix*8 + (s&7), p = s>>3 ----
  if (n < A_N) {
    float sh = 0.f;
#pragma unroll
    for (int s = 0; s < S_N; ++s) {
      const int pr = pos_l[s * 8 + n];
      sh += marg_l[((s >> 3) << 6) + pr * 8 + (s & 7)];
    }
    out[b * A_N + n] = sh * (1.f / 16.f) + b3[0] + vv[b];
  }
}

// ---------------------------------------------------------------------------
extern "C" void kernel_launch(void* const* d_in, const int* in_sizes, int n_in,
                              void* d_out, int out_size, void* d_ws,
                              size_t ws_size, hipStream_t stream) {
  const float* states   = (const float*)d_in[0];
  const float* agent_qs = (const float*)d_in[1];
  const float* W1       = (const float*)d_in[2];
  const float* b1       = (const float*)d_in[3];
  const float* W2       = (const float*)d_in[4];
  const float* b2       = (const float*)d_in[5];
  const float* W3       = (const float*)d_in[6];
  const float* b3       = (const float*)d_in[7];
  const float* Vw1      = (const float*)d_in[8];
  const float* Vb1      = (const float*)d_in[9];
  const float* Vw2      = (const float*)d_in[10];
  const float* Vb2      = (const float*)d_in[11];
  float* out = (float*)d_out;

  char* ws = (char*)d_ws;
  float*  sW     = (float*)(ws);                     // 1 MB
  float*  vv     = (float*)(ws + 1048576);           // 4 KB
  __bf16* W1b_bf = (__bf16*)(ws + 1052672);          // 64 KB
  __bf16* W2_bf  = (__bf16*)(ws + 1118208);          // 128 KB

  prep_pack_kernel<<<560, 256, 0, stream>>>(states, W1, b1, Vw1, Vb1, Vw2,
                                            Vb2, W2, sW, vv, W1b_bf, W2_bf);
  main_kernel<<<B_TOT, 256, 0, stream>>>(agent_qs, b2, W3, b3, sW, vv,
                                         W1b_bf, W2_bf, out);
}

// Round 9
// 117.845 us; speedup vs baseline: 1.0833x; 1.0122x over previous
//
#include <hip/hip_runtime.h>

// SQDDPG mixer, MI355X. Round 14: R7-exact (117.2 us session best) with ONE
// variable changed: layer-2 t-loop unroll 2 -> 4 (doubles in-flight bfr
// global loads + af ds_reads in the deepest loop; R11 PMC showed main
// latency-bound at MfmaUtil 17 / VALUBusy 28 / HBM 4%). R13's A-frag hoist
// reverted (neutral within the +-2 us noise band: 117.2/118.4/119.3).
//
// FROZEN (R8/R10/R11/R12/R13): main = 256 thr, (256,4), 1024 blocks all
// co-resident at 4/CU, <=128 regs (acc[4][2] + nh un-halves); prep = R7
// merged prep+pack. R4/R6: symmetric FETCH/WRITE = spill signature.
// Frozen validated facts (R2/R3): threefry partitionable, bits=o0^o1,
// counter (0, b*128+n); stable ranks; coalition slot j <- qs[inv_l[j]];
// output agent n reads prefix-row pos_l[n]; B-frag pack order: slot
// (t,u,L) elem j -> B[k=t*32+(L>>4)*8+j][n=u*16+(L&15)].
// Frozen validated facts (R6/R7): row map M-row = prefix*8+(s&7), pass
// p = s>>3; tile mt holds prefixes {2mt,2mt+1}; K-slice t contributes iff
// t<=mt; diagonal mask on = (q>>1)<=(l15>>3); h1 swizzle: unit index
// u = ub + ((q*4+r)^xr), reader lane Lsw = L ^ ((L>>3)&3); gather
// marg_l[(s>>3)*64 + pos*8 + (s&7)].

#define A_N   8
#define NA_N  16
#define S_N   16
#define SD    256
#define EMB   256
#define B_TOT 1024

typedef __bf16 bf16x8 __attribute__((ext_vector_type(8)));
typedef float  f32x4  __attribute__((ext_vector_type(4)));

__device__ __forceinline__ f32x4 splat4(float v) {
  f32x4 x; x[0] = v; x[1] = v; x[2] = v; x[3] = v; return x;
}
__device__ __forceinline__ bf16x8 zero8() {
  bf16x8 z;
#pragma unroll
  for (int j = 0; j < 8; ++j) z[j] = (__bf16)0.0f;
  return z;
}

// ---------------------------------------------------------------------------
// JAX threefry2x32, key = (0, 42); partitionable draw: bits = o0 ^ o1.
// ---------------------------------------------------------------------------
__device__ __forceinline__ float jax_uniform(unsigned idx) {
  const unsigned ks0 = 0u, ks1 = 42u, ks2 = 0x1BD11BDAu ^ 42u;
  unsigned x0 = 0u + ks0;
  unsigned x1 = idx + ks1;
#define TF_RND(r) { x0 += x1; x1 = (x1 << (r)) | (x1 >> (32 - (r))); x1 ^= x0; }
  TF_RND(13) TF_RND(15) TF_RND(26) TF_RND(6)  x0 += ks1; x1 += ks2 + 1u;
  TF_RND(17) TF_RND(29) TF_RND(16) TF_RND(24) x0 += ks2; x1 += ks0 + 2u;
  TF_RND(13) TF_RND(15) TF_RND(26) TF_RND(6)  x0 += ks0; x1 += ks1 + 3u;
  TF_RND(17) TF_RND(29) TF_RND(16) TF_RND(24) x0 += ks1; x1 += ks2 + 4u;
  TF_RND(13) TF_RND(15) TF_RND(26) TF_RND(6)  x0 += ks2; x1 += ks0 + 5u;
#undef TF_RND
  const unsigned bits = x0 ^ x1;
  return __uint_as_float((bits >> 9) | 0x3F800000u) - 1.0f;
}

// ---------------------------------------------------------------------------
// Merged prep (blocks 0..511: sW + V-net, 2 b each) + pack (blocks 512..559).
// Exact R7 form.
// ---------------------------------------------------------------------------
__global__ __launch_bounds__(256) void prep_pack_kernel(
    const float* __restrict__ states, const float* __restrict__ W1,
    const float* __restrict__ b1, const float* __restrict__ Vw1,
    const float* __restrict__ Vb1, const float* __restrict__ Vw2,
    const float* __restrict__ Vb2, const float* __restrict__ W2,
    float* __restrict__ sW, float* __restrict__ vout,
    __bf16* __restrict__ W1b_bf, __bf16* __restrict__ W2_bf) {
  __shared__ float st_l[2][SD];
  __shared__ float red_l[2][4];

  if (blockIdx.x >= 512) {  // ---- pack path ----
    const int ts = (blockIdx.x - 512) * 256 + threadIdx.x;  // 0..12287
    if (ts < 4096) {                                // W1 bottom: t=0..3
      const int t = ts >> 10, rem = ts & 1023, u = rem >> 6, Lp = rem & 63;
      const int qp = Lp >> 4, l15p = Lp & 15;
#pragma unroll
      for (int j = 0; j < 8; ++j) {
        const int k = t * 32 + qp * 8 + j, nn = u * 16 + l15p;
        W1b_bf[ts * 8 + j] = (__bf16)W1[(SD + k) * EMB + nn];
      }
    } else {                                        // W2: t=0..7
      const int ts2 = ts - 4096;
      const int t = ts2 >> 10, rem = ts2 & 1023, u = rem >> 6, Lp = rem & 63;
      const int qp = Lp >> 4, l15p = Lp & 15;
#pragma unroll
      for (int j = 0; j < 8; ++j) {
        const int k = t * 32 + qp * 8 + j, nn = u * 16 + l15p;
        W2_bf[ts2 * 8 + j] = (__bf16)W2[k * EMB + nn];
      }
    }
    return;
  }

  // ---- prep path ----
  const int b0 = blockIdx.x * 2;
  const int n = threadIdx.x;

#pragma unroll
  for (int i = 0; i < 2; ++i) st_l[i][n] = states[(b0 + i) * SD + n];
  __syncthreads();

  float aS[2], aV[2];
  const float b1n = b1[n], vb1n = Vb1[n];
#pragma unroll
  for (int i = 0; i < 2; ++i) { aS[i] = b1n; aV[i] = vb1n; }

#pragma unroll 8
  for (int k = 0; k < SD; ++k) {
    const float wv = W1[k * EMB + n];
    const float vw = Vw1[k * EMB + n];
#pragma unroll
    for (int i = 0; i < 2; ++i) {
      const float s = st_l[i][k];
      aS[i] = fmaf(s, wv, aS[i]);
      aV[i] = fmaf(s, vw, aV[i]);
    }
  }
#pragma unroll
  for (int i = 0; i < 2; ++i) sW[(b0 + i) * EMB + n] = aS[i];

  const float vw2 = Vw2[n];
#pragma unroll
  for (int i = 0; i < 2; ++i) {
    float c = fmaxf(aV[i], 0.f) * vw2;
#pragma unroll
    for (int off = 32; off; off >>= 1) c += __shfl_down(c, off);
    if ((n & 63) == 0) red_l[i][n >> 6] = c;
  }
  __syncthreads();
  if (n < 2)
    vout[b0 + n] = red_l[n][0] + red_l[n][1] + red_l[n][2] + red_l[n][3] + Vb2[0];
}

// ---------------------------------------------------------------------------
// Main: R7-exact except layer-2 t-loop unroll 4. 1024 blocks, 256 threads =
// 4 waves, (256,4). Two passes of M=64, prefix-major rows, triangular
// layer-1 (acc[4][2], nh-halved). Layer-2: nh-halved, psum carry.
// ---------------------------------------------------------------------------
__global__ __launch_bounds__(256, 4) void main_kernel(
    const float* __restrict__ agent_qs, const float* __restrict__ b2g,
    const float* __restrict__ W3, const float* __restrict__ b3,
    const float* __restrict__ sW, const float* __restrict__ vv,
    const __bf16* __restrict__ W1b_bf, const __bf16* __restrict__ W2_bf,
    float* __restrict__ out) {
  __shared__ bf16x8 h1_l[32 * 64];      // 32 KB: layer2 A-frags (swizzled)
  __shared__ __attribute__((aligned(16))) __bf16 qs_bf[A_N * NA_N];
  __shared__ float u_l[128];
  __shared__ int   inv_l[128];          // inv_l[s*8+a] = rank of agent a
  __shared__ int   pos_l[128];          // pos_l[s*8+r] = agent with rank r
  __shared__ float adv_part[4][64];
  __shared__ float marg_l[128];         // marg_l[p*64 + prefix*8 + (s&7)]

  const int b = blockIdx.x;
  const int n = threadIdx.x;
  const int w = n >> 6, L = n & 63, q = L >> 4, l15 = L & 15;
  const int s7 = l15 & 7;        // s low bits (A-frag / C-row role)
  const int sl = l15 >> 3;       // prefix low bit (A-frag side)
  const int jq = q >> 1;         // jcoal low bit
  const int na0 = (q & 1) * 8;   // action sub-block
  const int Lsw = L ^ ((L >> 3) & 3);  // swizzled layer-2 read lane

  if (n < 128) {
    qs_bf[n] = (__bf16)agent_qs[b * 128 + n];
    u_l[n] = jax_uniform((unsigned)(b * 128 + n));
  }
  __syncthreads();

  if (n < 128) {
    const int s = n >> 3, a = n & 7;
    const float u = u_l[n];
    int r = 0;
#pragma unroll
    for (int a2 = 0; a2 < A_N; ++a2) {
      const float u2 = u_l[s * 8 + a2];
      r += (u2 < u || (u2 == u && a2 < a)) ? 1 : 0;
    }
    inv_l[n] = r;
    pos_l[s * 8 + r] = a;
  }
  __syncthreads();

  // diagonal-tile mask: t==mt -> on iff jcoal<=prefix iff jq<=sl
  const bool diag_on = (jq <= sl);

#pragma unroll 1
  for (int p = 0; p < 2; ++p) {
    const int invbase = (p * 8 + s7) * 8;

    // ---- layer 1: triangular (64x128)@W1b(128x256); 2 un-halves ----
#pragma unroll 1
    for (int nh = 0; nh < 2; ++nh) {
      f32x4 acc[4][2];
#pragma unroll
      for (int i = 0; i < 2; ++i) {
        const float sv = sW[b * EMB + (w * 4 + nh * 2 + i) * 16 + l15];
#pragma unroll
        for (int mt = 0; mt < 4; ++mt) acc[mt][i] = splat4(sv);
      }
#pragma unroll
      for (int t = 0; t < 4; ++t) {
        const int ag = inv_l[invbase + 2 * t + jq];
        const bf16x8 afb = *(const bf16x8*)&qs_bf[ag * NA_N + na0];
        const bf16x8 afd = diag_on ? afb : zero8();
        bf16x8 bfr[2];
#pragma unroll
        for (int i = 0; i < 2; ++i)
          bfr[i] = *(const bf16x8*)
              &W1b_bf[((t * 16 + w * 4 + nh * 2 + i) * 64 + L) * 8];
#pragma unroll
        for (int mt = 0; mt < 4; ++mt) {
          if (mt < t) continue;  // compile-time folded: t>mt is exact zero
#pragma unroll
          for (int i = 0; i < 2; ++i)
            acc[mt][i] = __builtin_amdgcn_mfma_f32_16x16x32_bf16(
                (mt == t) ? afd : afb, bfr[i], acc[mt][i], 0, 0, 0);
        }
      }
      // relu -> bf16 swizzled scatter (conflict-free; R6-validated formula)
      __bf16* h1e = (__bf16*)h1_l;
#pragma unroll
      for (int i = 0; i < 2; ++i) {
        const int X = w * 4 + nh * 2 + i;
        const int hi = (X & 1) * 2 + sl;
        const int xr = (q >> 1) | ((hi & 1) << 1);
#pragma unroll
        for (int mt = 0; mt < 4; ++mt) {
          const int ub = ((X >> 1) * 4 + mt) * 64 + (hi << 4);
#pragma unroll
          for (int r = 0; r < 4; ++r) {
            const float v = fmaxf(acc[mt][i][r], 0.f);
            const int u = ub + ((q * 4 + r) ^ xr);
            h1e[u * 8 + s7] = (__bf16)v;
          }
        }
      }
    }
    __syncthreads();

    // ---- layer 2 + layer 3 partials: 2 un-halves, psum across halves ----
    float psum[4][4];
#pragma unroll
    for (int mt = 0; mt < 4; ++mt)
#pragma unroll
      for (int r = 0; r < 4; ++r) psum[mt][r] = 0.f;

#pragma unroll 1
    for (int nh = 0; nh < 2; ++nh) {
      f32x4 acc[4][2];
#pragma unroll
      for (int i = 0; i < 2; ++i) {
        const float bv = b2g[(w * 4 + nh * 2 + i) * 16 + l15];
#pragma unroll
        for (int mt = 0; mt < 4; ++mt) acc[mt][i] = splat4(bv);
      }
#pragma unroll 4
      for (int t = 0; t < 8; ++t) {
        bf16x8 bfr[2];
#pragma unroll
        for (int i = 0; i < 2; ++i)
          bfr[i] = *(const bf16x8*)
              &W2_bf[((t * 16 + w * 4 + nh * 2 + i) * 64 + L) * 8];
#pragma unroll
        for (int mt = 0; mt < 4; ++mt) {
          const bf16x8 af = h1_l[(t * 4 + mt) * 64 + Lsw];
#pragma unroll
          for (int i = 0; i < 2; ++i)
            acc[mt][i] = __builtin_amdgcn_mfma_f32_16x16x32_bf16(
                af, bfr[i], acc[mt][i], 0, 0, 0);
        }
      }
#pragma unroll
      for (int i = 0; i < 2; ++i) {
        const float w3v = W3[(w * 4 + nh * 2 + i) * 16 + l15];
#pragma unroll
        for (int mt = 0; mt < 4; ++mt)
#pragma unroll
          for (int r = 0; r < 4; ++r)
            psum[mt][r] = fmaf(fmaxf(acc[mt][i][r], 0.f), w3v, psum[mt][r]);
      }
    }

    // ---- reduce 16 cols per quad, combine waves via LDS ----
#pragma unroll
    for (int mt = 0; mt < 4; ++mt) {
#pragma unroll
      for (int r = 0; r < 4; ++r) {
        float sum = psum[mt][r];
#pragma unroll
        for (int off = 1; off < 16; off <<= 1) sum += __shfl_xor(sum, off);
        if (l15 == 0) adv_part[w][mt * 16 + q * 4 + r] = sum;
      }
    }
    __syncthreads();
    if (n < 64)
      marg_l[p * 64 + n] = adv_part[0][n] + adv_part[1][n] +
                           adv_part[2][n] + adv_part[3][n];
    __syncthreads();
  }

  // ---- gather: agent a at sample s -> row prefix*8 + (s&7), p = s>>3 ----
  if (n < A_N) {
    float sh = 0.f;
#pragma unroll
    for (int s = 0; s < S_N; ++s) {
      const int pr = pos_l[s * 8 + n];
      sh += marg_l[((s >> 3) << 6) + pr * 8 + (s & 7)];
    }
    out[b * A_N + n] = sh * (1.f / 16.f) + b3[0] + vv[b];
  }
}

// ---------------------------------------------------------------------------
extern "C" void kernel_launch(void* const* d_in, const int* in_sizes, int n_in,
                              void* d_out, int out_size, void* d_ws,
                              size_t ws_size, hipStream_t stream) {
  const float* states   = (const float*)d_in[0];
  const float* agent_qs = (const float*)d_in[1];
  const float* W1       = (const float*)d_in[2];
  const float* b1       = (const float*)d_in[3];
  const float* W2       = (const float*)d_in[4];
  const float* b2       = (const float*)d_in[5];
  const float* W3       = (const float*)d_in[6];
  const float* b3       = (const float*)d_in[7];
  const float* Vw1      = (const float*)d_in[8];
  const float* Vb1      = (const float*)d_in[9];
  const float* Vw2      = (const float*)d_in[10];
  const float* Vb2      = (const float*)d_in[11];
  float* out = (float*)d_out;

  char* ws = (char*)d_ws;
  float*  sW     = (float*)(ws);                     // 1 MB
  float*  vv     = (float*)(ws + 1048576);           // 4 KB
  __bf16* W1b_bf = (__bf16*)(ws + 1052672);          // 64 KB
  __bf16* W2_bf  = (__bf16*)(ws + 1118208);          // 128 KB

  prep_pack_kernel<<<560, 256, 0, stream>>>(states, W1, b1, Vw1, Vb1, Vw2,
                                            Vb2, W2, sW, vv, W1b_bf, W2_bf);
  main_kernel<<<B_TOT, 256, 0, stream>>>(agent_qs, b2, W3, b3, sW, vv,
                                         W1b_bf, W2_bf, out);
}